// Round 13
// baseline (196.350 us; speedup 1.0000x reference)
//
#include <hip/hip_runtime.h>
#include <stdint.h>

#define N_NODES 100000
#define FEAT 64
#define NB 64            // nodes per aggregation bucket (dstl in 6 bits)
#define SC_CHUNK 8192
#define NBKT 1563        // ceil(N_NODES / 64)
#define BKT_CAP 1400     // mean 1024, sigma 32 -> +11.7 sigma
#define RVN 6            // ceil(BKT_CAP / 256) register-held sorted entries
#define BIAS 512.0f      // makes all layer-2 outputs positive: float bits monotone
#define NT_NODES 256     // node tile per block (R13: fat register tile)
#define XT_STRIDE 260    // 256 + 4 pad (mult of 4 words: keeps b128 alignment)
// dynamic-LDS union: node 67*260 + 2*67*64 floats = 103984 B; bucket 6252 B
// 104 KB -> 1 block/CU; node loop is VALU-issue-bound (6 b128 per 128 FMAs)
#define SMEM_BYTES (67 * XT_STRIDE * 4 + 2 * 67 * 64 * 4)

typedef __attribute__((ext_vector_type(8))) _Float16 half8;  // 8 f16 (4 VGPRs)
typedef __attribute__((ext_vector_type(2))) _Float16 half2v;
typedef __attribute__((ext_vector_type(2))) __fp16 fp16x2;   // cvt_pkrtz result type
typedef __attribute__((ext_vector_type(4))) float f32x4;

// order-preserving float->u32 key (fallback path); 0 is an unreachable sentinel
__device__ __forceinline__ uint32_t enc_key(float f) {
    uint32_t u = __float_as_uint(f);
    return (u & 0x80000000u) ? ~u : (u | 0x80000000u);
}
__device__ __forceinline__ float dec_key(uint32_t k) {
    return __uint_as_float((k & 0x80000000u) ? (k & 0x7FFFFFFFu) : ~k);
}
__device__ __forceinline__ uint32_t pk_f16(float a, float b) {  // v_cvt_pkrtz
    union { fp16x2 h; uint32_t u; } cv;
    cv.h = __builtin_amdgcn_cvt_pkrtz(a, b);
    return cv.u;
}

// d_ws layout in 4-byte words:
// [0,4096)        W2T [64][64]         (fallback path only)
// [4096,8384)     AmB [67][64]         (unused in full path since R12)
// [8384,12672)    Bm  [67][64]         (unused in full path since R12)
// [12672,14720)   W2P f16[4096]        W2 pre-packed in B-fragment layout
// [16384,..)      U f16[N][64]; V f16[N][64]
// then gcnt u32[NBKT] (padded to 2048), sorted u32[NBKT * BKT_CAP]
#define W2T_OFF 0
#define AMB_OFF 4096
#define BM_OFF  8384
#define W2P_OFF 12672
#define U_OFF   16384
#define V_OFF   (U_OFF + N_NODES * FEAT / 2)
#define GCNT_OFF (U_OFF + N_NODES * FEAT)
#define SRT_OFF  (GCNT_OFF + 2048)

// fallback-path weight transpose only (full path no longer launches this)
__global__ __launch_bounds__(256) void transform_kernel(
    const float* __restrict__ W1, const float* __restrict__ W2,
    float* __restrict__ ws, int full)
{
    int i = blockIdx.x * 256 + threadIdx.x;
    if (i < 4096) {
        int c2 = i >> 6, c = i & 63;
        ws[W2T_OFF + i] = W2[c * 64 + c2];
    }
}

// ---------- FUSED node precompute + edge bucketing + W2P pack ---------------
// Block roles by blockIdx.x: [0, nBkt) bucket; [nBkt, nBkt+nodeBlocks) node;
// rest pack W2 into the agg B-fragment layout (16 blocks).
// R13: node path is a fat-register-tile GEMM — 8 nodes x 8 ch x 2 phases per
// thread (128 acc regs). Per k: 6 ds_read_b128 feed 128 FMA instrs -> per-CU
// LDS demand 288 cyc vs VALU 256 cyc (R12 was 432 vs 192: 2.25x LDS-bound,
// VALUBusy 25%, 55 us). 104 KB LDS -> 1 block/CU, 1 wave/SIMD: fine — 128
// independent FMAs/k saturate a SIMD solo; unroll-2 hides ds latency.
// Same k-ascending fmaf chain -> bit-identical U/V vs R11/R12.
__global__ __launch_bounds__(256) void nodebkt_kernel(
    const float* __restrict__ xyz, const float* __restrict__ feat,
    const float* __restrict__ b1, const float* __restrict__ W1,
    const float* __restrict__ W2, float* __restrict__ ws,
    uint16_t* __restrict__ U, uint16_t* __restrict__ V, int nN,
    const int* __restrict__ ei, uint32_t* __restrict__ gcnt,
    uint32_t* __restrict__ sorted, int nE, int nBkt, int nodeBlocks)
{
    extern __shared__ float smem[];
    int t = threadIdx.x;

    if ((int)blockIdx.x < nBkt) {
        // ---------------- bucket path (direct scattered write) ----------------
        uint32_t* hist = (uint32_t*)smem;      // NBKT cursors
        int e0 = blockIdx.x * SC_CHUNK;
        int cnt = min(SC_CHUNK, nE - e0);
        int cnt4 = cnt & ~3;

        for (int i = t; i < NBKT; i += 256) hist[i] = 0;
        __syncthreads();
        for (int i = t * 4; i < cnt4; i += 1024) {
            uint4 d4 = *(const uint4*)(ei + nE + e0 + i);
            atomicAdd(&hist[d4.x >> 6], 1u);
            atomicAdd(&hist[d4.y >> 6], 1u);
            atomicAdd(&hist[d4.z >> 6], 1u);
            atomicAdd(&hist[d4.w >> 6], 1u);
        }
        for (int i = cnt4 + t; i < cnt; i += 256)
            atomicAdd(&hist[ei[nE + e0 + i] >> 6], 1u);
        __syncthreads();
        for (int b = t; b < NBKT; b += 256) {
            uint32_t c = hist[b];
            hist[b] = c ? atomicAdd(&gcnt[b], c) : 0u;
        }
        __syncthreads();
        for (int i = t * 4; i < cnt4; i += 1024) {
            uint4 s4 = *(const uint4*)(ei + e0 + i);
            uint4 d4 = *(const uint4*)(ei + nE + e0 + i);
            uint32_t sa[4] = {(uint32_t)s4.x, (uint32_t)s4.y, (uint32_t)s4.z, (uint32_t)s4.w};
            uint32_t da[4] = {(uint32_t)d4.x, (uint32_t)d4.y, (uint32_t)d4.z, (uint32_t)d4.w};
            #pragma unroll
            for (int k = 0; k < 4; ++k) {
                uint32_t b = da[k] >> 6;
                uint32_t pos = atomicAdd(&hist[b], 1u);
                if (pos < BKT_CAP)
                    sorted[(size_t)b * BKT_CAP + pos] = sa[k] | ((da[k] & 63u) << 20);
            }
        }
        for (int i = cnt4 + t; i < cnt; i += 256) {
            uint32_t src = (uint32_t)ei[e0 + i];
            uint32_t dst = (uint32_t)ei[nE + e0 + i];
            uint32_t b = dst >> 6;
            uint32_t pos = atomicAdd(&hist[b], 1u);
            if (pos < BKT_CAP)
                sorted[(size_t)b * BKT_CAP + pos] = src | ((dst & 63u) << 20);
        }
        return;
    }

    int nb = (int)blockIdx.x - nBkt;
    if (nb >= nodeBlocks) {
        // ---------------- W2P pack path (16 blocks, 4096 f16) ----------------
        int p = (nb - nodeBlocks) * 256 + t;
        if (p < 4096) {
            int j = p & 7, c2lo = (p >> 3) & 15, quad = (p >> 7) & 3;
            int h = (p >> 9) & 1, n4 = (p >> 10) & 3;
            int k = h * 32 + quad * 8 + j;
            int n = n4 * 16 + c2lo;
            ((_Float16*)(ws + W2P_OFF))[p] = (_Float16)W2[k * 64 + n];
        }
        return;
    }

    // ---------------- node path: fat-register-tile LDS GEMM ----------------
    // U = f16(x @ (A-B) + b1), V = f16(x @ B)
    float* xt = smem;                        // 67 x XT_STRIDE, k-major
    float* wA = smem + 67 * XT_STRIDE;       // 67 x 64  (A-B, derived from W1)
    float* wB = wA + 67 * 64;                // 67 x 64  (B = W1[67:134])

    int nb0 = nb * NT_NODES;
    int rows = min(NT_NODES, nN - nb0);

    for (int i4 = t; i4 < 67 * 16; i4 += 256) {
        float4 a = *(const float4*)(W1 + i4 * 4);
        float4 b = *(const float4*)(W1 + 67 * 64 + i4 * 4);
        float4 d;
        d.x = a.x - b.x; d.y = a.y - b.y; d.z = a.z - b.z; d.w = a.w - b.w;
        *(float4*)(wA + i4 * 4) = d;
        *(float4*)(wB + i4 * 4) = b;
    }
    for (int g4 = t; g4 < rows * 16; g4 += 256) {
        int row = g4 >> 4, c4 = (g4 & 15) * 4;
        float4 v = *(const float4*)(feat + (size_t)(nb0 + row) * FEAT + c4);
        xt[(c4 + 0) * XT_STRIDE + row] = v.x;
        xt[(c4 + 1) * XT_STRIDE + row] = v.y;
        xt[(c4 + 2) * XT_STRIDE + row] = v.z;
        xt[(c4 + 3) * XT_STRIDE + row] = v.w;
    }
    for (int i = t; i < 3 * NT_NODES; i += 256) {
        int k3 = i >> 8, row = i & 255;
        float v = (row < rows) ? xyz[(size_t)(nb0 + row) * 3 + k3] : 0.0f;
        xt[(64 + k3) * XT_STRIDE + row] = v;
    }
    __syncthreads();

    int cb = (t & 7) * 8;         // 8-channel base (8 thread-slots cover 64 ch)
    int ng = (t >> 3) * 8;        // 8-node base   (32 groups cover 256 nodes)

    float accU[8][8], accV[8][8];
    #pragma unroll
    for (int c = 0; c < 8; ++c) {
        float bv = b1[cb + c];
        #pragma unroll
        for (int r = 0; r < 8; ++r) { accU[r][c] = bv; accV[r][c] = 0.0f; }
    }

    const float* xrow = xt + ng;
    #pragma unroll 2
    for (int k = 0; k < 67; ++k) {
        float4 x0 = *(const float4*)(xrow + k * XT_STRIDE);
        float4 x1 = *(const float4*)(xrow + k * XT_STRIDE + 4);
        float4 wa0 = *(const float4*)(wA + k * 64 + cb);
        float4 wa1 = *(const float4*)(wA + k * 64 + cb + 4);
        float4 wb0 = *(const float4*)(wB + k * 64 + cb);
        float4 wb1 = *(const float4*)(wB + k * 64 + cb + 4);
        float xv[8]  = {x0.x, x0.y, x0.z, x0.w, x1.x, x1.y, x1.z, x1.w};
        float wav[8] = {wa0.x, wa0.y, wa0.z, wa0.w, wa1.x, wa1.y, wa1.z, wa1.w};
        float wbv[8] = {wb0.x, wb0.y, wb0.z, wb0.w, wb1.x, wb1.y, wb1.z, wb1.w};
        #pragma unroll
        for (int r = 0; r < 8; ++r) {
            #pragma unroll
            for (int c = 0; c < 8; ++c) {
                accU[r][c] = fmaf(xv[r], wav[c], accU[r][c]);
                accV[r][c] = fmaf(xv[r], wbv[c], accV[r][c]);
            }
        }
    }

    #pragma unroll
    for (int r = 0; r < 8; ++r) {
        if (ng + r < rows) {
            size_t n = (size_t)(nb0 + ng + r);
            uint4 oU;
            oU.x = pk_f16(accU[r][0], accU[r][1]);
            oU.y = pk_f16(accU[r][2], accU[r][3]);
            oU.z = pk_f16(accU[r][4], accU[r][5]);
            oU.w = pk_f16(accU[r][6], accU[r][7]);
            *(uint4*)(U + n * FEAT + cb) = oU;
            uint4 oV;
            oV.x = pk_f16(accV[r][0], accV[r][1]);
            oV.y = pk_f16(accV[r][2], accV[r][3]);
            oV.z = pk_f16(accV[r][4], accV[r][5]);
            oV.w = pk_f16(accV[r][6], accV[r][7]);
            *(uint4*)(V + n * FEAT + cb) = oV;
        }
    }
}

// ---------- aggregation: LDS counting-sort + f16 MFMA (bias in acc) +
//            run-max + raw-bits LDS atomicMax (positive-float monotonicity)
#define LOADE(G, DSV, VV0, VV1, UU0, UU1) do {                               \
        int e_c_ = min((G) + el, cnt - 1);                                   \
        uint32_t val_ = ssrt[e_c_];                                          \
        DSV = *(const uint4*)(ssrt + (G) + quad * 4);                        \
        int src_ = (int)(val_ & 0xFFFFFu);                                   \
        const uint32_t* vr_ = (const uint32_t*)(V + (size_t)src_ * FEAT);    \
        VV0 = *(const uint4*)(vr_ + quad * 4);                               \
        VV1 = *(const uint4*)(vr_ + 16 + quad * 4);                          \
        const uint32_t* ur_ = ushare + (int)(val_ >> 20) * 32;               \
        UU0 = *(const uint4*)(ur_ + quad * 4);                               \
        UU1 = *(const uint4*)(ur_ + 16 + quad * 4);                          \
    } while (0)

__global__ __launch_bounds__(256) void agg_kernel(
    const uint32_t* __restrict__ gcnt, const uint32_t* __restrict__ sorted,
    const uint16_t* __restrict__ U, const uint16_t* __restrict__ V,
    const float* __restrict__ ws_w2p, const float* __restrict__ b2,
    float* __restrict__ out, int nN)
{
    __shared__ int      lmax[NB * 65];       // 16.6 KB, biased-float bits, 0 = none
    __shared__ uint32_t ushare[NB * 32];     // 8 KB: 64 node rows x 64 f16
    __shared__ uint32_t ssrt[BKT_CAP + 16];  // 5.7 KB (+16 pad for uint4 run read)
    __shared__ uint32_t shist[NB];

    int bkt = blockIdx.x;
    int nb0 = bkt * NB;
    int rows = min(NB, nN - nb0);
    int cnt = min((int)gcnt[bkt], BKT_CAP);
    int t = threadIdx.x;

    for (int i = t; i < NB * 65; i += 256) lmax[i] = 0;
    if (t < NB) shist[t] = 0;
    {
        const uint4* usrc4 = (const uint4*)(U + (size_t)nb0 * FEAT);
        for (int i = t; i < rows * 8; i += 256) ((uint4*)ushare)[i] = usrc4[i];
    }
    const uint32_t* bsrc = sorted + (size_t)bkt * BKT_CAP;
    __syncthreads();

    // single global read of the bucket segment, held in registers
    uint32_t rv[RVN];
    #pragma unroll
    for (int j = 0; j < RVN; ++j) {
        int i = t + j * 256;
        if (i < cnt) {
            uint32_t v = bsrc[i];
            rv[j] = v;
            atomicAdd(&shist[v >> 20], 1u);
        }
    }
    __syncthreads();
    if (t < NB) {   // wave-0 exclusive scan of 64 counters
        uint32_t v = shist[t];
        uint32_t run = v;
        #pragma unroll
        for (int d = 1; d < 64; d <<= 1) {
            uint32_t x = (uint32_t)__shfl_up((int)run, (unsigned)d, 64);
            if (t >= d) run += x;
        }
        shist[t] = run - v;                // exclusive start = cursor
    }
    __syncthreads();
    #pragma unroll
    for (int j = 0; j < RVN; ++j) {        // counting-sort placement from regs
        int i = t + j * 256;
        if (i < cnt) {
            uint32_t v = rv[j];
            uint32_t pos = atomicAdd(&shist[v >> 20], 1u);
            ssrt[pos] = v;
        }
    }
    __syncthreads();

    int lane = t & 63;
    int wave = t >> 6;
    int el = lane & 15, quad = lane >> 4;

    // B fragments (wave-uniform per lane): 8 frags of 16B
    const uint4* w2p = (const uint4*)ws_w2p;
    union { uint4 u4; half8 h8; } bfr[8];
    #pragma unroll
    for (int q8 = 0; q8 < 8; ++q8)              // q8 = n4*2 + h
        bfr[q8].u4 = w2p[(q8 * 4 + quad) * 16 + el];
    float b2v[4];
    #pragma unroll
    for (int n4 = 0; n4 < 4; ++n4) b2v[n4] = b2[n4 * 16 + el] + BIAS;

    const half2v zero2 = {(_Float16)0.0f, (_Float16)0.0f};

    // ---- pipelined main loop: iter g computes while iter g+64 loads ----
    uint4 dsv_c, vv_c0, vv_c1, uu_c0, uu_c1;
    int g = wave * 16;
    if (g < cnt) LOADE(g, dsv_c, vv_c0, vv_c1, uu_c0, uu_c1);

    #pragma unroll 1
    for (; g < cnt; g += 64) {
        int gn = g + 64;
        int gl = (gn < cnt) ? gn : g;       // last iter: redundant (valid) reload
        uint4 dsv_n, vv_n0, vv_n1, uu_n0, uu_n1;
        LOADE(gl, dsv_n, vv_n0, vv_n1, uu_n0, uu_n1);

        // build A fragments: relu(u+v) via packed f16 (2 ops per dword)
        union { uint4 u4; half8 h8; } afr[2];
        #pragma unroll
        for (int h = 0; h < 2; ++h) {
            uint4 uu = h ? uu_c1 : uu_c0;
            uint4 vv = h ? vv_c1 : vv_c0;
            uint32_t ua[4] = {uu.x, uu.y, uu.z, uu.w};
            uint32_t va[4] = {vv.x, vv.y, vv.z, vv.w};
            uint32_t pk[4];
            #pragma unroll
            for (int p = 0; p < 4; ++p) {
                union { uint32_t u; half2v h2; } cu, cv2, ct;
                cu.u = ua[p]; cv2.u = va[p];
                ct.h2 = __builtin_elementwise_max(cu.h2 + cv2.h2, zero2);
                pk[p] = ct.u;
            }
            afr[h].u4 = make_uint4(pk[0], pk[1], pk[2], pk[3]);
        }

        f32x4 acc[4];
        #pragma unroll
        for (int n4 = 0; n4 < 4; ++n4)      // bias+b2 pre-folded into accumulator
            acc[n4] = (f32x4){b2v[n4], b2v[n4], b2v[n4], b2v[n4]};
        #pragma unroll
        for (int n4 = 0; n4 < 4; ++n4) {
            acc[n4] = __builtin_amdgcn_mfma_f32_16x16x32_f16(afr[0].h8, bfr[n4*2+0].h8, acc[n4], 0, 0, 0);
            acc[n4] = __builtin_amdgcn_mfma_f32_16x16x32_f16(afr[1].h8, bfr[n4*2+1].h8, acc[n4], 0, 0, 0);
        }

        // dst_local for the 4 C-rows this lane holds (rows = quad*4+r), from the
        // sorted run itself; entries past cnt are pad-garbage but fully gated.
        int d0 = (int)(dsv_c.x >> 20), d1 = (int)(dsv_c.y >> 20);
        int d2 = (int)(dsv_c.z >> 20), d3 = (int)(dsv_c.w >> 20);
        int eb = g + quad * 4;
        bool ok0 = eb < cnt, ok1 = eb + 1 < cnt;
        bool ok2 = eb + 2 < cnt, ok3 = eb + 3 < cnt;
        bool m0 = (d0 == d1) & ok1;         // merge r into r+1 iff same dst & valid
        bool m1 = (d1 == d2) & ok2;
        bool m2 = (d2 == d3) & ok3;
        #pragma unroll
        for (int n4 = 0; n4 < 4; ++n4) {
            if (m0) acc[n4][1] = fmaxf(acc[n4][1], acc[n4][0]);
            if (m1) acc[n4][2] = fmaxf(acc[n4][2], acc[n4][1]);
            if (m2) acc[n4][3] = fmaxf(acc[n4][3], acc[n4][2]);
        }
        if (ok0 & !m0) {
            #pragma unroll
            for (int n4 = 0; n4 < 4; ++n4)
                atomicMax(&lmax[d0 * 65 + n4 * 16 + el], __float_as_int(acc[n4][0]));
        }
        if (ok1 & !m1) {
            #pragma unroll
            for (int n4 = 0; n4 < 4; ++n4)
                atomicMax(&lmax[d1 * 65 + n4 * 16 + el], __float_as_int(acc[n4][1]));
        }
        if (ok2 & !m2) {
            #pragma unroll
            for (int n4 = 0; n4 < 4; ++n4)
                atomicMax(&lmax[d2 * 65 + n4 * 16 + el], __float_as_int(acc[n4][2]));
        }
        if (ok3) {
            #pragma unroll
            for (int n4 = 0; n4 < 4; ++n4)
                atomicMax(&lmax[d3 * 65 + n4 * 16 + el], __float_as_int(acc[n4][3]));
        }

        dsv_c = dsv_n;
        vv_c0 = vv_n0; vv_c1 = vv_n1;
        uu_c0 = uu_n0; uu_c1 = uu_n1;
    }
    __syncthreads();

    for (int i = t * 4; i < rows * FEAT; i += 1024) {
        int r = i >> 6, c = i & 63;
        int lb = r * 65 + c;
        int k0 = lmax[lb + 0], k1 = lmax[lb + 1];
        int k2 = lmax[lb + 2], k3 = lmax[lb + 3];
        float4 o;
        o.x = k0 ? (__int_as_float(k0) - BIAS) : 0.0f;
        o.y = k1 ? (__int_as_float(k1) - BIAS) : 0.0f;
        o.z = k2 ? (__int_as_float(k2) - BIAS) : 0.0f;
        o.w = k3 ? (__int_as_float(k3) - BIAS) : 0.0f;
        *(float4*)(out + (size_t)(nb0 + r) * FEAT + c) = o;
    }
}
#undef LOADE

// ---------- fallback (small ws): fused per-edge kernel (known-correct) ----------
__device__ __forceinline__ void rank1_update(
    float* __restrict__ h, float xi, float d,
    const float* __restrict__ A, const float* __restrict__ B)
{
    #pragma unroll
    for (int c = 0; c < FEAT; ++c)
        h[c] = fmaf(xi, A[c], fmaf(d, B[c], h[c]));
}

__global__ __launch_bounds__(256) void edge_fused_kernel(
    const float* __restrict__ xyz, const float* __restrict__ feat,
    const int* __restrict__ ei,
    const float* __restrict__ W1, const float* __restrict__ b1,
    const float* __restrict__ ws, const float* __restrict__ b2,
    uint32_t* __restrict__ keys, int nE)
{
    int e = blockIdx.x * 256 + threadIdx.x;
    if (e >= nE) return;
    int src = ei[e];
    int dst = ei[nE + e];
    const float* __restrict__ W2T = ws + W2T_OFF;

    float h[FEAT];
    #pragma unroll
    for (int c = 0; c < FEAT; ++c) h[c] = b1[c];

    const float* fi = feat + (size_t)dst * FEAT;
    const float* fj = feat + (size_t)src * FEAT;
    #pragma unroll 1
    for (int k = 0; k < 64; k += 4) {
        float4 a = *(const float4*)(fi + k);
        float4 b = *(const float4*)(fj + k);
        rank1_update(h, a.x, b.x - a.x, W1 + (k + 0) * 64, W1 + (67 + k + 0) * 64);
        rank1_update(h, a.y, b.y - a.y, W1 + (k + 1) * 64, W1 + (67 + k + 1) * 64);
        rank1_update(h, a.z, b.z - a.z, W1 + (k + 2) * 64, W1 + (67 + k + 2) * 64);
        rank1_update(h, a.w, b.w - a.w, W1 + (k + 3) * 64, W1 + (67 + k + 3) * 64);
    }
    {
        const float* pi = xyz + (size_t)dst * 3;
        const float* pj = xyz + (size_t)src * 3;
        #pragma unroll
        for (int k3 = 0; k3 < 3; ++k3) {
            float xi = pi[k3];
            rank1_update(h, xi, pj[k3] - xi, W1 + (64 + k3) * 64, W1 + (131 + k3) * 64);
        }
    }
    #pragma unroll
    for (int c = 0; c < FEAT; ++c) h[c] = fmaxf(h[c], 0.0f);

    uint32_t* krow = keys + (size_t)dst * FEAT;
    #pragma unroll 1
    for (int c2 = 0; c2 < FEAT; c2 += 4) {
        float o0 = b2[c2 + 0], o1 = b2[c2 + 1];
        float o2 = b2[c2 + 2], o3 = b2[c2 + 3];
        const float* w0 = W2T + (c2 + 0) * 64;
        const float* w1 = W2T + (c2 + 1) * 64;
        const float* w2 = W2T + (c2 + 2) * 64;
        const float* w3 = W2T + (c2 + 3) * 64;
        #pragma unroll
        for (int c = 0; c < FEAT; ++c) {
            float hv = h[c];
            o0 = fmaf(hv, w0[c], o0);
            o1 = fmaf(hv, w1[c], o1);
            o2 = fmaf(hv, w2[c], o2);
            o3 = fmaf(hv, w3[c], o3);
        }
        uint32_t k0 = enc_key(o0), k1 = enc_key(o1);
        uint32_t k2 = enc_key(o2), k3 = enc_key(o3);
        uint4 cur = *(const uint4*)(krow + c2);
        if (k0 > cur.x) atomicMax(&krow[c2 + 0], k0);
        if (k1 > cur.y) atomicMax(&krow[c2 + 1], k1);
        if (k2 > cur.z) atomicMax(&krow[c2 + 2], k2);
        if (k3 > cur.w) atomicMax(&krow[c2 + 3], k3);
    }
}

__global__ __launch_bounds__(256) void decode_kernel(
    uint32_t* __restrict__ keys, int n4)
{
    int i = blockIdx.x * 256 + threadIdx.x;
    if (i >= n4) return;
    uint4 k = ((const uint4*)keys)[i];
    float4 r;
    r.x = k.x ? dec_key(k.x) : 0.0f;
    r.y = k.y ? dec_key(k.y) : 0.0f;
    r.z = k.z ? dec_key(k.z) : 0.0f;
    r.w = k.w ? dec_key(k.w) : 0.0f;
    ((float4*)keys)[i] = r;
}

extern "C" void kernel_launch(void* const* d_in, const int* in_sizes, int n_in,
                              void* d_out, int out_size, void* d_ws, size_t ws_size,
                              hipStream_t stream)
{
    const float* xyz  = (const float*)d_in[0];
    const float* feat = (const float*)d_in[1];
    const int*   ei   = (const int*)d_in[2];
    const float* W1   = (const float*)d_in[3];
    const float* b1   = (const float*)d_in[4];
    const float* W2   = (const float*)d_in[5];
    const float* b2   = (const float*)d_in[6];

    int nE = in_sizes[2] / 2;
    float* ws = (float*)d_ws;

    size_t need_words = (size_t)SRT_OFF + (size_t)NBKT * BKT_CAP;
    int full = (ws_size >= need_words * 4) ? 1 : 0;

    if (full) {
        uint16_t* U = (uint16_t*)(ws + U_OFF);
        uint16_t* V = (uint16_t*)(ws + V_OFF);
        uint32_t* gcnt   = (uint32_t*)(ws + GCNT_OFF);
        uint32_t* sorted = (uint32_t*)(ws + SRT_OFF);

        hipMemsetAsync(gcnt, 0, NBKT * sizeof(uint32_t), stream);
        int nBkt = (nE + SC_CHUNK - 1) / SC_CHUNK;
        int nodeBlocks = (N_NODES + NT_NODES - 1) / NT_NODES;
        int packBlocks = 16;
        nodebkt_kernel<<<nBkt + nodeBlocks + packBlocks, 256, SMEM_BYTES, stream>>>(
            xyz, feat, b1, W1, W2, ws, U, V, N_NODES, ei, gcnt, sorted, nE,
            nBkt, nodeBlocks);
        agg_kernel<<<NBKT, 256, 0, stream>>>(
            gcnt, sorted, U, V, ws + W2P_OFF, b2, (float*)d_out, N_NODES);
    } else {
        uint32_t* keys = (uint32_t*)d_out;
        transform_kernel<<<16, 256, 0, stream>>>(W1, W2, ws, 0);
        hipMemsetAsync(d_out, 0, (size_t)out_size * sizeof(float), stream);
        edge_fused_kernel<<<(nE + 255) / 256, 256, 0, stream>>>(
            xyz, feat, ei, W1, b1, ws, b2, keys, nE);
        decode_kernel<<<(out_size / 4 + 255) / 256, 256, 0, stream>>>(
            keys, out_size / 4);
    }
}

// Round 14
// 172.833 us; speedup vs baseline: 1.1361x; 1.1361x over previous
//
#include <hip/hip_runtime.h>
#include <stdint.h>

#define N_NODES 100000
#define FEAT 64
#define NB 64            // nodes per aggregation bucket (dstl in 6 bits)
#define SC_CHUNK 8192
#define NBKT 1563        // ceil(N_NODES / 64)
#define BKT_CAP 1400     // mean 1024, sigma 32 -> +11.7 sigma
#define RVN 6            // ceil(BKT_CAP / 256) register-held sorted entries
#define BIAS 512.0f      // makes all layer-2 outputs positive: float bits monotone
#define NT_NODES 128     // node tile per block (R14: revert to R11 optimum)
#define XT_STRIDE 132    // 128 + 4 pad (mult of 4 words: keeps b128 alignment)
#define USTRIDE 36       // agg ushare row stride in dwords (144B: 16B-aligned,
                         // bank-start rotates 4/row -> 2-way max, free; 32 was
                         // a 16-way ds_read_b128 conflict = 1.43M SQ_LDS_BANK_CONFLICT)
// dynamic-LDS union: node 67*132 + 2*67*64 floats = 69680 B; bucket 6252 B
// 69.7 KB -> 2 blocks/CU. Tile sweep R11/R12/R13 (8 waves/r1.5, 12/r2.25,
// 4/r1.125) = 55/55/80 us: occupancy x FMA-per-read product optimum is here.
#define SMEM_BYTES (67 * XT_STRIDE * 4 + 2 * 67 * 64 * 4)

typedef __attribute__((ext_vector_type(8))) _Float16 half8;  // 8 f16 (4 VGPRs)
typedef __attribute__((ext_vector_type(2))) _Float16 half2v;
typedef __attribute__((ext_vector_type(2))) __fp16 fp16x2;   // cvt_pkrtz result type
typedef __attribute__((ext_vector_type(4))) float f32x4;

// order-preserving float->u32 key (fallback path); 0 is an unreachable sentinel
__device__ __forceinline__ uint32_t enc_key(float f) {
    uint32_t u = __float_as_uint(f);
    return (u & 0x80000000u) ? ~u : (u | 0x80000000u);
}
__device__ __forceinline__ float dec_key(uint32_t k) {
    return __uint_as_float((k & 0x80000000u) ? (k & 0x7FFFFFFFu) : ~k);
}
__device__ __forceinline__ uint32_t pk_f16(float a, float b) {  // v_cvt_pkrtz
    union { fp16x2 h; uint32_t u; } cv;
    cv.h = __builtin_amdgcn_cvt_pkrtz(a, b);
    return cv.u;
}

// d_ws layout in 4-byte words:
// [0,4096)        W2T [64][64]         (fallback path only)
// [4096,8384)     AmB [67][64]         (unused in full path since R12)
// [8384,12672)    Bm  [67][64]         (unused in full path since R12)
// [12672,14720)   W2P f16[4096]        W2 pre-packed in B-fragment layout
// [16384,..)      U f16[N][64]; V f16[N][64]
// then gcnt u32[NBKT] (padded to 2048), sorted u32[NBKT * BKT_CAP]
#define W2T_OFF 0
#define AMB_OFF 4096
#define BM_OFF  8384
#define W2P_OFF 12672
#define U_OFF   16384
#define V_OFF   (U_OFF + N_NODES * FEAT / 2)
#define GCNT_OFF (U_OFF + N_NODES * FEAT)
#define SRT_OFF  (GCNT_OFF + 2048)

// fallback-path weight transpose only (full path no longer launches this)
__global__ __launch_bounds__(256) void transform_kernel(
    const float* __restrict__ W1, const float* __restrict__ W2,
    float* __restrict__ ws, int full)
{
    int i = blockIdx.x * 256 + threadIdx.x;
    if (i < 4096) {
        int c2 = i >> 6, c = i & 63;
        ws[W2T_OFF + i] = W2[c * 64 + c2];
    }
}

// ---------- FUSED node precompute + edge bucketing + W2P pack ---------------
// Block roles by blockIdx.x: [0, nBkt) bucket; [nBkt, nBkt+nodeBlocks) node;
// rest pack W2 into the agg B-fragment layout (16 blocks).
// Bucket blocks FIRST: latency-bound global-atomic chains start immediately;
// node blocks (VALU-dense LDS-GEMM) fill in and hide that latency.
// Node path: R11 geometry (8 nodes x 4 ch x 2 phases, 4 b128 per 64 FMAs,
// 2 blocks/CU) — the tile-sweep optimum; R13's fatter tile (1 blk/CU) lost
// all latency hiding (VALUBusy 17%, +25 us).
__global__ __launch_bounds__(256) void nodebkt_kernel(
    const float* __restrict__ xyz, const float* __restrict__ feat,
    const float* __restrict__ b1, const float* __restrict__ W1,
    const float* __restrict__ W2, float* __restrict__ ws,
    uint16_t* __restrict__ U, uint16_t* __restrict__ V, int nN,
    const int* __restrict__ ei, uint32_t* __restrict__ gcnt,
    uint32_t* __restrict__ sorted, int nE, int nBkt, int nodeBlocks)
{
    extern __shared__ float smem[];
    int t = threadIdx.x;

    if ((int)blockIdx.x < nBkt) {
        // ---------------- bucket path (direct scattered write) ----------------
        uint32_t* hist = (uint32_t*)smem;      // NBKT cursors
        int e0 = blockIdx.x * SC_CHUNK;
        int cnt = min(SC_CHUNK, nE - e0);
        int cnt4 = cnt & ~3;

        for (int i = t; i < NBKT; i += 256) hist[i] = 0;
        __syncthreads();
        for (int i = t * 4; i < cnt4; i += 1024) {
            uint4 d4 = *(const uint4*)(ei + nE + e0 + i);
            atomicAdd(&hist[d4.x >> 6], 1u);
            atomicAdd(&hist[d4.y >> 6], 1u);
            atomicAdd(&hist[d4.z >> 6], 1u);
            atomicAdd(&hist[d4.w >> 6], 1u);
        }
        for (int i = cnt4 + t; i < cnt; i += 256)
            atomicAdd(&hist[ei[nE + e0 + i] >> 6], 1u);
        __syncthreads();
        for (int b = t; b < NBKT; b += 256) {
            uint32_t c = hist[b];
            hist[b] = c ? atomicAdd(&gcnt[b], c) : 0u;
        }
        __syncthreads();
        for (int i = t * 4; i < cnt4; i += 1024) {
            uint4 s4 = *(const uint4*)(ei + e0 + i);
            uint4 d4 = *(const uint4*)(ei + nE + e0 + i);
            uint32_t sa[4] = {(uint32_t)s4.x, (uint32_t)s4.y, (uint32_t)s4.z, (uint32_t)s4.w};
            uint32_t da[4] = {(uint32_t)d4.x, (uint32_t)d4.y, (uint32_t)d4.z, (uint32_t)d4.w};
            #pragma unroll
            for (int k = 0; k < 4; ++k) {
                uint32_t b = da[k] >> 6;
                uint32_t pos = atomicAdd(&hist[b], 1u);
                if (pos < BKT_CAP)
                    sorted[(size_t)b * BKT_CAP + pos] = sa[k] | ((da[k] & 63u) << 20);
            }
        }
        for (int i = cnt4 + t; i < cnt; i += 256) {
            uint32_t src = (uint32_t)ei[e0 + i];
            uint32_t dst = (uint32_t)ei[nE + e0 + i];
            uint32_t b = dst >> 6;
            uint32_t pos = atomicAdd(&hist[b], 1u);
            if (pos < BKT_CAP)
                sorted[(size_t)b * BKT_CAP + pos] = src | ((dst & 63u) << 20);
        }
        return;
    }

    int nb = (int)blockIdx.x - nBkt;
    if (nb >= nodeBlocks) {
        // ---------------- W2P pack path (16 blocks, 4096 f16) ----------------
        int p = (nb - nodeBlocks) * 256 + t;
        if (p < 4096) {
            int j = p & 7, c2lo = (p >> 3) & 15, quad = (p >> 7) & 3;
            int h = (p >> 9) & 1, n4 = (p >> 10) & 3;
            int k = h * 32 + quad * 8 + j;
            int n = n4 * 16 + c2lo;
            ((_Float16*)(ws + W2P_OFF))[p] = (_Float16)W2[k * 64 + n];
        }
        return;
    }

    // ---------------- node path: all-LDS GEMM tile (R11 geometry) ----------
    // U = f16(x @ (A-B) + b1), V = f16(x @ B); 8-node x 4-ch x 2-phase reg
    // tile; 4 ds_read_b128 per 64 FMAs; no global access in the k-loop.
    float* xt = smem;                        // 67 x XT_STRIDE, k-major
    float* wA = smem + 67 * XT_STRIDE;       // 67 x 64  (A-B, derived from W1)
    float* wB = wA + 67 * 64;                // 67 x 64  (B = W1[67:134])

    int nb0 = nb * NT_NODES;
    int rows = min(NT_NODES, nN - nb0);

    for (int i4 = t; i4 < 67 * 16; i4 += 256) {
        float4 a = *(const float4*)(W1 + i4 * 4);
        float4 b = *(const float4*)(W1 + 67 * 64 + i4 * 4);
        float4 d;
        d.x = a.x - b.x; d.y = a.y - b.y; d.z = a.z - b.z; d.w = a.w - b.w;
        *(float4*)(wA + i4 * 4) = d;
        *(float4*)(wB + i4 * 4) = b;
    }
    for (int g4 = t; g4 < rows * 16; g4 += 256) {
        int row = g4 >> 4, c4 = (g4 & 15) * 4;
        float4 v = *(const float4*)(feat + (size_t)(nb0 + row) * FEAT + c4);
        xt[(c4 + 0) * XT_STRIDE + row] = v.x;
        xt[(c4 + 1) * XT_STRIDE + row] = v.y;
        xt[(c4 + 2) * XT_STRIDE + row] = v.z;
        xt[(c4 + 3) * XT_STRIDE + row] = v.w;
    }
    for (int i = t; i < 3 * NT_NODES; i += 256) {
        int k3 = i >> 7, row = i & 127;
        float v = (row < rows) ? xyz[(size_t)(nb0 + row) * 3 + k3] : 0.0f;
        xt[(64 + k3) * XT_STRIDE + row] = v;
    }
    __syncthreads();

    int cb = (t & 15) * 4;        // 4-channel base (16 threads cover 64 ch)
    int ng = (t >> 4) * 8;        // 8-node base   (16 groups cover 128 nodes)

    float accU[8][4], accV[8][4];
    #pragma unroll
    for (int c = 0; c < 4; ++c) {
        float bv = b1[cb + c];
        #pragma unroll
        for (int r = 0; r < 8; ++r) { accU[r][c] = bv; accV[r][c] = 0.0f; }
    }

    const float* xrow = xt + ng;
    #pragma unroll 2
    for (int k = 0; k < 67; ++k) {
        float4 x0 = *(const float4*)(xrow + k * XT_STRIDE);
        float4 x1 = *(const float4*)(xrow + k * XT_STRIDE + 4);
        float4 wa = *(const float4*)(wA + k * 64 + cb);
        float4 wb = *(const float4*)(wB + k * 64 + cb);
        float xv[8] = {x0.x, x0.y, x0.z, x0.w, x1.x, x1.y, x1.z, x1.w};
        float wav[4] = {wa.x, wa.y, wa.z, wa.w};
        float wbv[4] = {wb.x, wb.y, wb.z, wb.w};
        #pragma unroll
        for (int r = 0; r < 8; ++r) {
            #pragma unroll
            for (int c = 0; c < 4; ++c) {
                accU[r][c] = fmaf(xv[r], wav[c], accU[r][c]);
                accV[r][c] = fmaf(xv[r], wbv[c], accV[r][c]);
            }
        }
    }

    #pragma unroll
    for (int r = 0; r < 8; ++r) {
        if (ng + r < rows) {
            size_t n = (size_t)(nb0 + ng + r);
            uint2 oU; oU.x = pk_f16(accU[r][0], accU[r][1]);
                      oU.y = pk_f16(accU[r][2], accU[r][3]);
            *(uint2*)(U + n * FEAT + cb) = oU;
            uint2 oV; oV.x = pk_f16(accV[r][0], accV[r][1]);
                      oV.y = pk_f16(accV[r][2], accV[r][3]);
            *(uint2*)(V + n * FEAT + cb) = oV;
        }
    }
}

// ---------- aggregation: LDS counting-sort + f16 MFMA (bias in acc) +
//            run-max + raw-bits LDS atomicMax (positive-float monotonicity)
// R14: ushare rows padded 32->36 dwords (USTRIDE): the 128B row stride made
// every U-row ds_read_b128 a 16-way bank conflict (1.43M SQ_LDS_BANK_CONFLICT).
#define LOADE(G, DSV, VV0, VV1, UU0, UU1) do {                               \
        int e_c_ = min((G) + el, cnt - 1);                                   \
        uint32_t val_ = ssrt[e_c_];                                          \
        DSV = *(const uint4*)(ssrt + (G) + quad * 4);                        \
        int src_ = (int)(val_ & 0xFFFFFu);                                   \
        const uint32_t* vr_ = (const uint32_t*)(V + (size_t)src_ * FEAT);    \
        VV0 = *(const uint4*)(vr_ + quad * 4);                               \
        VV1 = *(const uint4*)(vr_ + 16 + quad * 4);                          \
        const uint32_t* ur_ = ushare + (int)(val_ >> 20) * USTRIDE;          \
        UU0 = *(const uint4*)(ur_ + quad * 4);                               \
        UU1 = *(const uint4*)(ur_ + 16 + quad * 4);                          \
    } while (0)

__global__ __launch_bounds__(256) void agg_kernel(
    const uint32_t* __restrict__ gcnt, const uint32_t* __restrict__ sorted,
    const uint16_t* __restrict__ U, const uint16_t* __restrict__ V,
    const float* __restrict__ ws_w2p, const float* __restrict__ b2,
    float* __restrict__ out, int nN)
{
    __shared__ int      lmax[NB * 65];       // 16.6 KB, biased-float bits, 0 = none
    __shared__ uint32_t ushare[NB * USTRIDE];// 9.2 KB: 64 rows x 64 f16, padded
    __shared__ uint32_t ssrt[BKT_CAP + 16];  // 5.7 KB (+16 pad for uint4 run read)
    __shared__ uint32_t shist[NB];

    int bkt = blockIdx.x;
    int nb0 = bkt * NB;
    int rows = min(NB, nN - nb0);
    int cnt = min((int)gcnt[bkt], BKT_CAP);
    int t = threadIdx.x;

    for (int i = t; i < NB * 65; i += 256) lmax[i] = 0;
    if (t < NB) shist[t] = 0;
    {
        const uint4* usrc4 = (const uint4*)(U + (size_t)nb0 * FEAT);
        for (int i = t; i < rows * 8; i += 256) {
            int row = i >> 3, q = i & 7;
            *(uint4*)(ushare + row * USTRIDE + q * 4) = usrc4[i];
        }
    }
    const uint32_t* bsrc = sorted + (size_t)bkt * BKT_CAP;
    __syncthreads();

    // single global read of the bucket segment, held in registers
    uint32_t rv[RVN];
    #pragma unroll
    for (int j = 0; j < RVN; ++j) {
        int i = t + j * 256;
        if (i < cnt) {
            uint32_t v = bsrc[i];
            rv[j] = v;
            atomicAdd(&shist[v >> 20], 1u);
        }
    }
    __syncthreads();
    if (t < NB) {   // wave-0 exclusive scan of 64 counters
        uint32_t v = shist[t];
        uint32_t run = v;
        #pragma unroll
        for (int d = 1; d < 64; d <<= 1) {
            uint32_t x = (uint32_t)__shfl_up((int)run, (unsigned)d, 64);
            if (t >= d) run += x;
        }
        shist[t] = run - v;                // exclusive start = cursor
    }
    __syncthreads();
    #pragma unroll
    for (int j = 0; j < RVN; ++j) {        // counting-sort placement from regs
        int i = t + j * 256;
        if (i < cnt) {
            uint32_t v = rv[j];
            uint32_t pos = atomicAdd(&shist[v >> 20], 1u);
            ssrt[pos] = v;
        }
    }
    __syncthreads();

    int lane = t & 63;
    int wave = t >> 6;
    int el = lane & 15, quad = lane >> 4;

    // B fragments (wave-uniform per lane): 8 frags of 16B
    const uint4* w2p = (const uint4*)ws_w2p;
    union { uint4 u4; half8 h8; } bfr[8];
    #pragma unroll
    for (int q8 = 0; q8 < 8; ++q8)              // q8 = n4*2 + h
        bfr[q8].u4 = w2p[(q8 * 4 + quad) * 16 + el];
    float b2v[4];
    #pragma unroll
    for (int n4 = 0; n4 < 4; ++n4) b2v[n4] = b2[n4 * 16 + el] + BIAS;

    const half2v zero2 = {(_Float16)0.0f, (_Float16)0.0f};

    // ---- pipelined main loop: iter g computes while iter g+64 loads ----
    uint4 dsv_c, vv_c0, vv_c1, uu_c0, uu_c1;
    int g = wave * 16;
    if (g < cnt) LOADE(g, dsv_c, vv_c0, vv_c1, uu_c0, uu_c1);

    #pragma unroll 1
    for (; g < cnt; g += 64) {
        int gn = g + 64;
        int gl = (gn < cnt) ? gn : g;       // last iter: redundant (valid) reload
        uint4 dsv_n, vv_n0, vv_n1, uu_n0, uu_n1;
        LOADE(gl, dsv_n, vv_n0, vv_n1, uu_n0, uu_n1);

        // build A fragments: relu(u+v) via packed f16 (2 ops per dword)
        union { uint4 u4; half8 h8; } afr[2];
        #pragma unroll
        for (int h = 0; h < 2; ++h) {
            uint4 uu = h ? uu_c1 : uu_c0;
            uint4 vv = h ? vv_c1 : vv_c0;
            uint32_t ua[4] = {uu.x, uu.y, uu.z, uu.w};
            uint32_t va[4] = {vv.x, vv.y, vv.z, vv.w};
            uint32_t pk[4];
            #pragma unroll
            for (int p = 0; p < 4; ++p) {
                union { uint32_t u; half2v h2; } cu, cv2, ct;
                cu.u = ua[p]; cv2.u = va[p];
                ct.h2 = __builtin_elementwise_max(cu.h2 + cv2.h2, zero2);
                pk[p] = ct.u;
            }
            afr[h].u4 = make_uint4(pk[0], pk[1], pk[2], pk[3]);
        }

        f32x4 acc[4];
        #pragma unroll
        for (int n4 = 0; n4 < 4; ++n4)      // bias+b2 pre-folded into accumulator
            acc[n4] = (f32x4){b2v[n4], b2v[n4], b2v[n4], b2v[n4]};
        #pragma unroll
        for (int n4 = 0; n4 < 4; ++n4) {
            acc[n4] = __builtin_amdgcn_mfma_f32_16x16x32_f16(afr[0].h8, bfr[n4*2+0].h8, acc[n4], 0, 0, 0);
            acc[n4] = __builtin_amdgcn_mfma_f32_16x16x32_f16(afr[1].h8, bfr[n4*2+1].h8, acc[n4], 0, 0, 0);
        }

        // dst_local for the 4 C-rows this lane holds (rows = quad*4+r), from the
        // sorted run itself; entries past cnt are pad-garbage but fully gated.
        int d0 = (int)(dsv_c.x >> 20), d1 = (int)(dsv_c.y >> 20);
        int d2 = (int)(dsv_c.z >> 20), d3 = (int)(dsv_c.w >> 20);
        int eb = g + quad * 4;
        bool ok0 = eb < cnt, ok1 = eb + 1 < cnt;
        bool ok2 = eb + 2 < cnt, ok3 = eb + 3 < cnt;
        bool m0 = (d0 == d1) & ok1;         // merge r into r+1 iff same dst & valid
        bool m1 = (d1 == d2) & ok2;
        bool m2 = (d2 == d3) & ok3;
        #pragma unroll
        for (int n4 = 0; n4 < 4; ++n4) {
            if (m0) acc[n4][1] = fmaxf(acc[n4][1], acc[n4][0]);
            if (m1) acc[n4][2] = fmaxf(acc[n4][2], acc[n4][1]);
            if (m2) acc[n4][3] = fmaxf(acc[n4][3], acc[n4][2]);
        }
        if (ok0 & !m0) {
            #pragma unroll
            for (int n4 = 0; n4 < 4; ++n4)
                atomicMax(&lmax[d0 * 65 + n4 * 16 + el], __float_as_int(acc[n4][0]));
        }
        if (ok1 & !m1) {
            #pragma unroll
            for (int n4 = 0; n4 < 4; ++n4)
                atomicMax(&lmax[d1 * 65 + n4 * 16 + el], __float_as_int(acc[n4][1]));
        }
        if (ok2 & !m2) {
            #pragma unroll
            for (int n4 = 0; n4 < 4; ++n4)
                atomicMax(&lmax[d2 * 65 + n4 * 16 + el], __float_as_int(acc[n4][2]));
        }
        if (ok3) {
            #pragma unroll
            for (int n4 = 0; n4 < 4; ++n4)
                atomicMax(&lmax[d3 * 65 + n4 * 16 + el], __float_as_int(acc[n4][3]));
        }

        dsv_c = dsv_n;
        vv_c0 = vv_n0; vv_c1 = vv_n1;
        uu_c0 = uu_n0; uu_c1 = uu_n1;
    }
    __syncthreads();

    for (int i = t * 4; i < rows * FEAT; i += 1024) {
        int r = i >> 6, c = i & 63;
        int lb = r * 65 + c;
        int k0 = lmax[lb + 0], k1 = lmax[lb + 1];
        int k2 = lmax[lb + 2], k3 = lmax[lb + 3];
        float4 o;
        o.x = k0 ? (__int_as_float(k0) - BIAS) : 0.0f;
        o.y = k1 ? (__int_as_float(k1) - BIAS) : 0.0f;
        o.z = k2 ? (__int_as_float(k2) - BIAS) : 0.0f;
        o.w = k3 ? (__int_as_float(k3) - BIAS) : 0.0f;
        *(float4*)(out + (size_t)(nb0 + r) * FEAT + c) = o;
    }
}
#undef LOADE

// ---------- fallback (small ws): fused per-edge kernel (known-correct) ----------
__device__ __forceinline__ void rank1_update(
    float* __restrict__ h, float xi, float d,
    const float* __restrict__ A, const float* __restrict__ B)
{
    #pragma unroll
    for (int c = 0; c < FEAT; ++c)
        h[c] = fmaf(xi, A[c], fmaf(d, B[c], h[c]));
}

__global__ __launch_bounds__(256) void edge_fused_kernel(
    const float* __restrict__ xyz, const float* __restrict__ feat,
    const int* __restrict__ ei,
    const float* __restrict__ W1, const float* __restrict__ b1,
    const float* __restrict__ ws, const float* __restrict__ b2,
    uint32_t* __restrict__ keys, int nE)
{
    int e = blockIdx.x * 256 + threadIdx.x;
    if (e >= nE) return;
    int src = ei[e];
    int dst = ei[nE + e];
    const float* __restrict__ W2T = ws + W2T_OFF;

    float h[FEAT];
    #pragma unroll
    for (int c = 0; c < FEAT; ++c) h[c] = b1[c];

    const float* fi = feat + (size_t)dst * FEAT;
    const float* fj = feat + (size_t)src * FEAT;
    #pragma unroll 1
    for (int k = 0; k < 64; k += 4) {
        float4 a = *(const float4*)(fi + k);
        float4 b = *(const float4*)(fj + k);
        rank1_update(h, a.x, b.x - a.x, W1 + (k + 0) * 64, W1 + (67 + k + 0) * 64);
        rank1_update(h, a.y, b.y - a.y, W1 + (k + 1) * 64, W1 + (67 + k + 1) * 64);
        rank1_update(h, a.z, b.z - a.z, W1 + (k + 2) * 64, W1 + (67 + k + 2) * 64);
        rank1_update(h, a.w, b.w - a.w, W1 + (k + 3) * 64, W1 + (67 + k + 3) * 64);
    }
    {
        const float* pi = xyz + (size_t)dst * 3;
        const float* pj = xyz + (size_t)src * 3;
        #pragma unroll
        for (int k3 = 0; k3 < 3; ++k3) {
            float xi = pi[k3];
            rank1_update(h, xi, pj[k3] - xi, W1 + (64 + k3) * 64, W1 + (131 + k3) * 64);
        }
    }
    #pragma unroll
    for (int c = 0; c < FEAT; ++c) h[c] = fmaxf(h[c], 0.0f);

    uint32_t* krow = keys + (size_t)dst * FEAT;
    #pragma unroll 1
    for (int c2 = 0; c2 < FEAT; c2 += 4) {
        float o0 = b2[c2 + 0], o1 = b2[c2 + 1];
        float o2 = b2[c2 + 2], o3 = b2[c2 + 3];
        const float* w0 = W2T + (c2 + 0) * 64;
        const float* w1 = W2T + (c2 + 1) * 64;
        const float* w2 = W2T + (c2 + 2) * 64;
        const float* w3 = W2T + (c2 + 3) * 64;
        #pragma unroll
        for (int c = 0; c < FEAT; ++c) {
            float hv = h[c];
            o0 = fmaf(hv, w0[c], o0);
            o1 = fmaf(hv, w1[c], o1);
            o2 = fmaf(hv, w2[c], o2);
            o3 = fmaf(hv, w3[c], o3);
        }
        uint32_t k0 = enc_key(o0), k1 = enc_key(o1);
        uint32_t k2 = enc_key(o2), k3 = enc_key(o3);
        uint4 cur = *(const uint4*)(krow + c2);
        if (k0 > cur.x) atomicMax(&krow[c2 + 0], k0);
        if (k1 > cur.y) atomicMax(&krow[c2 + 1], k1);
        if (k2 > cur.z) atomicMax(&krow[c2 + 2], k2);
        if (k3 > cur.w) atomicMax(&krow[c2 + 3], k3);
    }
}

__global__ __launch_bounds__(256) void decode_kernel(
    uint32_t* __restrict__ keys, int n4)
{
    int i = blockIdx.x * 256 + threadIdx.x;
    if (i >= n4) return;
    uint4 k = ((const uint4*)keys)[i];
    float4 r;
    r.x = k.x ? dec_key(k.x) : 0.0f;
    r.y = k.y ? dec_key(k.y) : 0.0f;
    r.z = k.z ? dec_key(k.z) : 0.0f;
    r.w = k.w ? dec_key(k.w) : 0.0f;
    ((float4*)keys)[i] = r;
}

extern "C" void kernel_launch(void* const* d_in, const int* in_sizes, int n_in,
                              void* d_out, int out_size, void* d_ws, size_t ws_size,
                              hipStream_t stream)
{
    const float* xyz  = (const float*)d_in[0];
    const float* feat = (const float*)d_in[1];
    const int*   ei   = (const int*)d_in[2];
    const float* W1   = (const float*)d_in[3];
    const float* b1   = (const float*)d_in[4];
    const float* W2   = (const float*)d_in[5];
    const float* b2   = (const float*)d_in[6];

    int nE = in_sizes[2] / 2;
    float* ws = (float*)d_ws;

    size_t need_words = (size_t)SRT_OFF + (size_t)NBKT * BKT_CAP;
    int full = (ws_size >= need_words * 4) ? 1 : 0;

    if (full) {
        uint16_t* U = (uint16_t*)(ws + U_OFF);
        uint16_t* V = (uint16_t*)(ws + V_OFF);
        uint32_t* gcnt   = (uint32_t*)(ws + GCNT_OFF);
        uint32_t* sorted = (uint32_t*)(ws + SRT_OFF);

        hipMemsetAsync(gcnt, 0, NBKT * sizeof(uint32_t), stream);
        int nBkt = (nE + SC_CHUNK - 1) / SC_CHUNK;
        int nodeBlocks = (N_NODES + NT_NODES - 1) / NT_NODES;
        int packBlocks = 16;
        nodebkt_kernel<<<nBkt + nodeBlocks + packBlocks, 256, SMEM_BYTES, stream>>>(
            xyz, feat, b1, W1, W2, ws, U, V, N_NODES, ei, gcnt, sorted, nE,
            nBkt, nodeBlocks);
        agg_kernel<<<NBKT, 256, 0, stream>>>(
            gcnt, sorted, U, V, ws + W2P_OFF, b2, (float*)d_out, N_NODES);
    } else {
        uint32_t* keys = (uint32_t*)d_out;
        transform_kernel<<<16, 256, 0, stream>>>(W1, W2, ws, 0);
        hipMemsetAsync(d_out, 0, (size_t)out_size * sizeof(float), stream);
        edge_fused_kernel<<<(nE + 255) / 256, 256, 0, stream>>>(
            xyz, feat, ei, W1, b1, ws, b2, keys, nE);
        decode_kernel<<<(out_size / 4 + 255) / 256, 256, 0, stream>>>(
            keys, out_size / 4);
    }
}